// Round 14
// baseline (74.805 us; speedup 1.0000x reference)
//
#include <hip/hip_runtime.h>
#include <hip/hip_bf16.h>

// AgreementRouting, 5-kernel full-machine plan, 18-way IC partition.
// B=128, IC=1152, OC=10, D=16, 3 iters, f32 in/out.
//
// R13 -> R14: kernels have NO cross-block sync, so grid size is free.
// 8 parts (1024 blocks) capped occupancy at 4 blk/CU = 16 waves/CU (50%),
// and R6's profile showed the result: 870 GB/s, 21.9% occupancy, latency-
// bound. Now 18 parts (2304 blocks, 64 slices/part, 4 slices/group):
// 9 blk/CU available -> occupancy VGPR-limited (~28 waves/CU), 1.75x TLP.
// I-kernels issue all 4 slice-loads upfront (20 dwords in flight, static
// register names) before computing.
//
// A  (2304x256): stream f32 u ONCE (NT) -> u16 bf16 copy + s0 partials.
// I<T>(2304x256): vsum = sum_{t<T} squash(reduce s_t partials) (tiny);
//                 stream OWN u16 slice-range -> s_T partials.
//                 Logits: bb_T = b_in + <u, vsum> (linearity, R2-proven).
// F  (80x256): reduce s3 partials + squash -> out.
//
// R12 lesson (3x-confirmed): in-kernel cross-block sync ~200us/phase on
// MI355X (non-coherent per-XCD L2s) -> kernel boundaries are the sync.
// R11 lesson: register-resident u spills (allocator caps 128 VGPR).
//
// Lane scheme per 16-lane group (slice = 10x16 f32): l=tid&15, h=l>>3.
// Lane owns (j=2k+h, d=2(l&7)..2(l&7)+1), k=0..4 == float offset 32k+2l.
// Cross-lane in hot loops: all DPP (VALU pipe), R6-proven.

#define B_     128
#define IC_    1152
#define OC_    10
#define ROW_   160
#define WPS_   80      // bf16 dwords per slice
#define PARTS_ 18
#define SPB_   64      // slices per part
#define UPB_   4       // slices per 16-lane group
#define SOUT_  20480   // B_*ROW_

typedef float v2f __attribute__((ext_vector_type(2)));

__device__ __forceinline__ float bf_lo(uint32_t w) { return __uint_as_float(w << 16); }
__device__ __forceinline__ float bf_hi(uint32_t w) { return __uint_as_float(w & 0xffff0000u); }

template<int CTRL>
__device__ __forceinline__ float dppf(float x) {
    return __int_as_float(__builtin_amdgcn_update_dpp(
        0, __float_as_int(x), CTRL, 0xF, 0xF, true));
}
__device__ __forceinline__ float dpp_sum8(float x) {
    x += dppf<0xB1>(x);    // quad_perm [1,0,3,2]  (xor1)
    x += dppf<0x4E>(x);    // quad_perm [2,3,0,1]  (xor2)
    x += dppf<0x141>(x);   // row_half_mirror      (cross-quad within 8)
    return x;
}
__device__ __forceinline__ float softmax10(float own[5]) {
    float m = own[0];
#pragma unroll
    for (int k = 1; k < 5; ++k) m = fmaxf(m, own[k]);
    m = fmaxf(m, dppf<0x128>(m));          // row_ror:8 == xor8 within 16
    float sum = 0.f;
#pragma unroll
    for (int k = 0; k < 5; ++k) { own[k] = __expf(own[k] - m); sum += own[k]; }
    sum += dppf<0x128>(sum);
    return 1.f / sum;
}

// ---------------- Kernel A ----------------
__global__ __launch_bounds__(256) void a_kernel(
    const float* __restrict__ u, const float* __restrict__ b_in,
    uint32_t* __restrict__ u16, float* __restrict__ s_part)
{
    const int bid = blockIdx.x, tid = threadIdx.x;
    const int l = tid & 15, h = l >> 3, g = tid >> 4;
    const int b = bid / PARTS_, part = bid % PARTS_;
    const int wave = tid >> 6, lane = tid & 63;

    __shared__ float red[4][ROW_];
    __shared__ float b_lds[SPB_ * OC_];    // 640 floats

#pragma unroll
    for (int it = 0; it < 3; ++it) {
        int idx = it * 256 + tid;
        if (idx < SPB_ * OC_) b_lds[idx] = b_in[part * SPB_ * OC_ + idx];
    }
    __syncthreads();

    float2 sc[5];
#pragma unroll
    for (int k = 0; k < 5; ++k) { sc[k].x = 0.f; sc[k].y = 0.f; }
#pragma unroll
    for (int uu = 0; uu < UPB_; ++uu) {
        const int su = uu * 16 + g;
        const int i  = part * SPB_ + su;
        const v2f* up = (const v2f*)(u + (size_t)(b * IC_ + i) * ROW_ + 2 * l);
        v2f uv[5];
#pragma unroll
        for (int k = 0; k < 5; ++k) uv[k] = __builtin_nontemporal_load(up + 16 * k);

        uint32_t* wp = u16 + (size_t)(b * IC_ + i) * WPS_;
#pragma unroll
        for (int k = 0; k < 5; ++k) {
            __hip_bfloat16 bx = __float2bfloat16(uv[k].x);
            __hip_bfloat16 by = __float2bfloat16(uv[k].y);
            wp[16 * k + l] = ((uint32_t)(*(const uint16_t*)&by) << 16) |
                              (uint32_t)(*(const uint16_t*)&bx);
        }
        float own[5];
#pragma unroll
        for (int k = 0; k < 5; ++k) own[k] = b_lds[su * OC_ + 2 * k + h];
        const float inv = softmax10(own);
#pragma unroll
        for (int k = 0; k < 5; ++k) {
            float c = own[k] * inv;
            sc[k].x += c * uv[k].x; sc[k].y += c * uv[k].y;
        }
    }
#pragma unroll
    for (int k = 0; k < 5; ++k) {
        sc[k].x += __shfl_xor(sc[k].x, 16); sc[k].y += __shfl_xor(sc[k].y, 16);
        sc[k].x += __shfl_xor(sc[k].x, 32); sc[k].y += __shfl_xor(sc[k].y, 32);
    }
    if (lane < 16) {
#pragma unroll
        for (int k = 0; k < 5; ++k)
            *(float2*)&red[wave][32 * k + 2 * l] = sc[k];
    }
    __syncthreads();
    if (tid < ROW_) {
        float t = red[0][tid] + red[1][tid] + red[2][tid] + red[3][tid];
        s_part[(size_t)((0 * B_ + b) * PARTS_ + part) * ROW_ + tid] = t;
    }
}

// ---------------- Kernel I<T> ----------------
template<int T>
__global__ __launch_bounds__(256) void i_kernel(
    const uint32_t* __restrict__ u16, const float* __restrict__ b_in,
    const float* __restrict__ s_part, float* __restrict__ s_next)
{
    const int bid = blockIdx.x, tid = threadIdx.x;
    const int l = tid & 15, h = l >> 3, g = tid >> 4;
    const int b = bid / PARTS_, part = bid % PARTS_;
    const int wave = tid >> 6, lane = tid & 63;

    __shared__ float red[4][ROW_];
    __shared__ float v_lds[ROW_];
    __shared__ float b_lds[SPB_ * OC_];

#pragma unroll
    for (int it = 0; it < 3; ++it) {
        int idx = it * 256 + tid;
        if (idx < SPB_ * OC_) b_lds[idx] = b_in[part * SPB_ * OC_ + idx];
    }

    if (tid < ROW_) {
        float vsum = 0.f;
#pragma unroll
        for (int t = 0; t < T; ++t) {
            const float* sp = s_part + (size_t)((t * B_ + b) * PARTS_) * ROW_;
            float x = 0.f;
#pragma unroll
            for (int p = 0; p < PARTS_; ++p) x += sp[p * ROW_ + tid];
            float sq = x * x;
            sq += __shfl_xor(sq, 1, 16);
            sq += __shfl_xor(sq, 2, 16);
            sq += __shfl_xor(sq, 4, 16);
            sq += __shfl_xor(sq, 8, 16);
            vsum += (sq / (1.f + sq)) * x * rsqrtf(sq + 1e-8f);
        }
        v_lds[tid] = vsum;
    }
    __syncthreads();

    float2 vv[5];
#pragma unroll
    for (int k = 0; k < 5; ++k)
        vv[k] = *(const float2*)&v_lds[32 * k + 2 * l];

    // issue ALL 4 slice-loads upfront (20 dwords in flight, static names)
    const uint32_t* wp0 = u16 + (size_t)(b * IC_ + part * SPB_ + 0 * 16 + g) * WPS_;
    const uint32_t* wp1 = u16 + (size_t)(b * IC_ + part * SPB_ + 1 * 16 + g) * WPS_;
    const uint32_t* wp2 = u16 + (size_t)(b * IC_ + part * SPB_ + 2 * 16 + g) * WPS_;
    const uint32_t* wp3 = u16 + (size_t)(b * IC_ + part * SPB_ + 3 * 16 + g) * WPS_;
    uint32_t uw0[5], uw1[5], uw2[5], uw3[5];
#pragma unroll
    for (int k = 0; k < 5; ++k) uw0[k] = wp0[16 * k + l];
#pragma unroll
    for (int k = 0; k < 5; ++k) uw1[k] = wp1[16 * k + l];
#pragma unroll
    for (int k = 0; k < 5; ++k) uw2[k] = wp2[16 * k + l];
#pragma unroll
    for (int k = 0; k < 5; ++k) uw3[k] = wp3[16 * k + l];

    float2 sc[5];
#pragma unroll
    for (int k = 0; k < 5; ++k) { sc[k].x = 0.f; sc[k].y = 0.f; }

#define B_COMP(UW, uu) do {                                                 \
        const int su_ = (uu) * 16 + g;                                      \
        float own[5];                                                       \
        _Pragma("unroll")                                                   \
        for (int k = 0; k < 5; ++k) own[k] = b_lds[su_ * OC_ + 2 * k + h];  \
        _Pragma("unroll")                                                   \
        for (int k = 0; k < 5; ++k) {                                       \
            float pd = bf_lo(UW[k]) * vv[k].x + bf_hi(UW[k]) * vv[k].y;     \
            own[k] += dpp_sum8(pd);                                         \
        }                                                                   \
        const float inv = softmax10(own);                                   \
        _Pragma("unroll")                                                   \
        for (int k = 0; k < 5; ++k) {                                       \
            float c = own[k] * inv;                                         \
            sc[k].x += c * bf_lo(UW[k]); sc[k].y += c * bf_hi(UW[k]);       \
        }                                                                   \
    } while (0)

    B_COMP(uw0, 0);
    B_COMP(uw1, 1);
    B_COMP(uw2, 2);
    B_COMP(uw3, 3);
#undef B_COMP

#pragma unroll
    for (int k = 0; k < 5; ++k) {
        sc[k].x += __shfl_xor(sc[k].x, 16); sc[k].y += __shfl_xor(sc[k].y, 16);
        sc[k].x += __shfl_xor(sc[k].x, 32); sc[k].y += __shfl_xor(sc[k].y, 32);
    }
    if (lane < 16) {
#pragma unroll
        for (int k = 0; k < 5; ++k)
            *(float2*)&red[wave][32 * k + 2 * l] = sc[k];
    }
    __syncthreads();
    if (tid < ROW_) {
        float t = red[0][tid] + red[1][tid] + red[2][tid] + red[3][tid];
        s_next[(size_t)(b * PARTS_ + part) * ROW_ + tid] = t;
    }
}

// ---------------- Kernel F ----------------
__global__ __launch_bounds__(256) void f_kernel(
    const float* __restrict__ s_part, float* __restrict__ out)
{
    const int idx = blockIdx.x * 256 + threadIdx.x;   // 0..SOUT_-1
    const int b = idx / ROW_, r = idx % ROW_;
    const float* sp = s_part + (size_t)(b * PARTS_) * ROW_;
    float x = 0.f;
#pragma unroll
    for (int p = 0; p < PARTS_; ++p) x += sp[p * ROW_ + r];
    float sq = x * x;
    sq += __shfl_xor(sq, 1, 16);
    sq += __shfl_xor(sq, 2, 16);
    sq += __shfl_xor(sq, 4, 16);
    sq += __shfl_xor(sq, 8, 16);
    out[idx] = (sq / (1.f + sq)) * x * rsqrtf(sq + 1e-8f);
}

extern "C" void kernel_launch(void* const* d_in, const int* in_sizes, int n_in,
                              void* d_out, int out_size, void* d_ws, size_t ws_size,
                              hipStream_t stream) {
    const float* u    = (const float*)d_in[0];
    const float* b_in = (const float*)d_in[1];
    float* out = (float*)d_out;

    float*    s_part = (float*)d_ws;   // 4 phases * B*18*160 f32 = 5.9 MB
    uint32_t* u16    = (uint32_t*)(s_part + (size_t)4 * B_ * PARTS_ * ROW_); // 47.2 MB

    const dim3 blk(256);
    const dim3 grid(B_ * PARTS_);      // 2304

    a_kernel<<<grid, blk, 0, stream>>>(u, b_in, u16, s_part);
    i_kernel<1><<<grid, blk, 0, stream>>>(u16, b_in, s_part,
                                          s_part + (size_t)1 * B_ * PARTS_ * ROW_);
    i_kernel<2><<<grid, blk, 0, stream>>>(u16, b_in, s_part,
                                          s_part + (size_t)2 * B_ * PARTS_ * ROW_);
    i_kernel<3><<<grid, blk, 0, stream>>>(u16, b_in, s_part,
                                          s_part + (size_t)3 * B_ * PARTS_ * ROW_);
    f_kernel<<<dim3(SOUT_ / 256), blk, 0, stream>>>(
        s_part + (size_t)3 * B_ * PARTS_ * ROW_, out);
}

// Round 15
// 68.885 us; speedup vs baseline: 1.0859x; 1.0859x over previous
//
#include <hip/hip_runtime.h>
#include <hip/hip_bf16.h>

// AgreementRouting, 5-kernel full-machine plan (R13 base, 8-way partition)
// + atomic phase-reduction + v_acc chain + hoisted u16 loads.
// B=128, IC=1152, OC=10, D=16, 3 iters, f32 in/out.
//
// A  (1024x256): zero s_red[1..3] (61440 f32, done before I1 by kernel
//     boundary) + stream f32 u ONCE (NT) -> u16 bf16 copy + s0 partials.
// I<T>(1024x256): prologue: T==1: vsum = squash(reduce8 s0 partials);
//     T>1: vsum = v_acc[T-1] + squash(s_red[T-1] row)  [1-2 row reads].
//     part==0 stores v_acc[T] (consumed by T+1 only -> race-free).
//     Stream OWN u16 eighth; logits bb_T = b_in + <u, vsum> (linearity).
//     Output: atomicAdd partial row into s_red[T] (8-way/elem, R1-proven).
//     First u16 slice-loads issued BEFORE prologue (latency hidden; the
//     prologue-ending __syncthreads drains vmcnt for both).
// F  (80x256): out = squash(s_red[3]).
//
// Lessons enforced: no in-kernel cross-block sync (R12: ~200us/phase);
// no register-resident u (R11: spills at 128-VGPR cap); PARTS_=8 (R14:
// 18-way partition regressed).
//
// Lane scheme per 16-lane group (slice = 10x16 f32): l=tid&15, h=l>>3.
// Lane owns (j=2k+h, d=2(l&7)..2(l&7)+1), k=0..4 == float offset 32k+2l.
// Cross-lane in hot loops: all DPP (VALU pipe), R6-proven.

#define B_     128
#define IC_    1152
#define OC_    10
#define ROW_   160
#define WPS_   80      // bf16 dwords per slice
#define PARTS_ 8
#define SPB_   144     // slices per part
#define UPB_   9       // slices per 16-lane group
#define SOUT_  20480   // B_*ROW_

typedef float v2f __attribute__((ext_vector_type(2)));

__device__ __forceinline__ float bf_lo(uint32_t w) { return __uint_as_float(w << 16); }
__device__ __forceinline__ float bf_hi(uint32_t w) { return __uint_as_float(w & 0xffff0000u); }

template<int CTRL>
__device__ __forceinline__ float dppf(float x) {
    return __int_as_float(__builtin_amdgcn_update_dpp(
        0, __float_as_int(x), CTRL, 0xF, 0xF, true));
}
__device__ __forceinline__ float dpp_sum8(float x) {
    x += dppf<0xB1>(x);    // quad_perm [1,0,3,2]  (xor1)
    x += dppf<0x4E>(x);    // quad_perm [2,3,0,1]  (xor2)
    x += dppf<0x141>(x);   // row_half_mirror      (cross-quad within 8)
    return x;
}
__device__ __forceinline__ float softmax10(float own[5]) {
    float m = own[0];
#pragma unroll
    for (int k = 1; k < 5; ++k) m = fmaxf(m, own[k]);
    m = fmaxf(m, dppf<0x128>(m));          // row_ror:8 == xor8 within 16
    float sum = 0.f;
#pragma unroll
    for (int k = 0; k < 5; ++k) { own[k] = __expf(own[k] - m); sum += own[k]; }
    sum += dppf<0x128>(sum);
    return 1.f / sum;
}
// squash scalar given x (per tid<ROW_ thread), 16-lane-group sum via shfl
__device__ __forceinline__ float squash_row(float x) {
    float sq = x * x;
    sq += __shfl_xor(sq, 1, 16);
    sq += __shfl_xor(sq, 2, 16);
    sq += __shfl_xor(sq, 4, 16);
    sq += __shfl_xor(sq, 8, 16);
    return (sq / (1.f + sq)) * x * rsqrtf(sq + 1e-8f);
}

// ---------------- Kernel A ----------------
__global__ __launch_bounds__(256) void a_kernel(
    const float* __restrict__ u, const float* __restrict__ b_in,
    uint32_t* __restrict__ u16, float* __restrict__ s0_part,
    float* __restrict__ s_red)   // s_red[1..3], 3*SOUT_ floats, zeroed here
{
    const int bid = blockIdx.x, tid = threadIdx.x;
    const int l = tid & 15, h = l >> 3, g = tid >> 4;
    const int b = bid >> 3, part = bid & 7;
    const int wave = tid >> 6, lane = tid & 63;

    // zero the atomic accumulators for this launch (I1 runs after boundary)
    const int gidx = bid * 256 + tid;
    if (gidx < 3 * SOUT_) s_red[gidx] = 0.f;

    __shared__ float red[4][ROW_];
    __shared__ float b_lds[SPB_ * OC_];

#pragma unroll
    for (int it = 0; it < 6; ++it) {
        int idx = it * 256 + tid;
        if (idx < SPB_ * OC_) b_lds[idx] = b_in[part * SPB_ * OC_ + idx];
    }
    __syncthreads();

    float2 sc[5];
#pragma unroll
    for (int k = 0; k < 5; ++k) { sc[k].x = 0.f; sc[k].y = 0.f; }
#pragma unroll
    for (int uu = 0; uu < UPB_; ++uu) {
        const int su = uu * 16 + g;
        const int i  = part * SPB_ + su;
        const v2f* up = (const v2f*)(u + (size_t)(b * IC_ + i) * ROW_ + 2 * l);
        v2f uv[5];
#pragma unroll
        for (int k = 0; k < 5; ++k) uv[k] = __builtin_nontemporal_load(up + 16 * k);

        uint32_t* wp = u16 + (size_t)(b * IC_ + i) * WPS_;
#pragma unroll
        for (int k = 0; k < 5; ++k) {
            __hip_bfloat16 bx = __float2bfloat16(uv[k].x);
            __hip_bfloat16 by = __float2bfloat16(uv[k].y);
            wp[16 * k + l] = ((uint32_t)(*(const uint16_t*)&by) << 16) |
                              (uint32_t)(*(const uint16_t*)&bx);
        }
        float own[5];
#pragma unroll
        for (int k = 0; k < 5; ++k) own[k] = b_lds[su * OC_ + 2 * k + h];
        const float inv = softmax10(own);
#pragma unroll
        for (int k = 0; k < 5; ++k) {
            float c = own[k] * inv;
            sc[k].x += c * uv[k].x; sc[k].y += c * uv[k].y;
        }
    }
#pragma unroll
    for (int k = 0; k < 5; ++k) {
        sc[k].x += __shfl_xor(sc[k].x, 16); sc[k].y += __shfl_xor(sc[k].y, 16);
        sc[k].x += __shfl_xor(sc[k].x, 32); sc[k].y += __shfl_xor(sc[k].y, 32);
    }
    if (lane < 16) {
#pragma unroll
        for (int k = 0; k < 5; ++k)
            *(float2*)&red[wave][32 * k + 2 * l] = sc[k];
    }
    __syncthreads();
    if (tid < ROW_) {
        float t = red[0][tid] + red[1][tid] + red[2][tid] + red[3][tid];
        s0_part[(size_t)(b * PARTS_ + part) * ROW_ + tid] = t;
    }
}

// ---------------- Kernel I<T> ----------------
// s_red_prev = s_red[T-1] (null concept for T=1), v_in = v_acc[T-1],
// v_out = v_acc[T] (unused for T=3), s_out = s_red[T].
template<int T>
__global__ __launch_bounds__(256) void i_kernel(
    const uint32_t* __restrict__ u16, const float* __restrict__ b_in,
    const float* __restrict__ s0_part, const float* __restrict__ s_red_prev,
    const float* __restrict__ v_in, float* __restrict__ v_out,
    float* __restrict__ s_out)
{
    const int bid = blockIdx.x, tid = threadIdx.x;
    const int l = tid & 15, h = l >> 3, g = tid >> 4;
    const int b = bid >> 3, part = bid & 7;
    const int wave = tid >> 6, lane = tid & 63;

    __shared__ float red[4][ROW_];
    __shared__ float v_lds[ROW_];
    __shared__ float b_lds[SPB_ * OC_];

#define B_LOAD(UW, uu) do {                                                 \
        const int su_ = (uu) * 16 + g;                                      \
        const uint32_t* wp_ = u16 + (size_t)(b * IC_ + part * SPB_ + su_) * WPS_; \
        _Pragma("unroll")                                                   \
        for (int k = 0; k < 5; ++k) UW[k] = wp_[16 * k + l];                \
    } while (0)

    // issue first two slice-loads BEFORE the prologue (latency hidden under
    // the prologue's global reads; the __syncthreads drains vmcnt for both)
    uint32_t uwA[5], uwB[5];
    B_LOAD(uwA, 0);
    B_LOAD(uwB, 1);

#pragma unroll
    for (int it = 0; it < 6; ++it) {
        int idx = it * 256 + tid;
        if (idx < SPB_ * OC_) b_lds[idx] = b_in[part * SPB_ * OC_ + idx];
    }

    if (tid < ROW_) {
        float vsum;
        if (T == 1) {
            const float* sp = s0_part + (size_t)(b * PARTS_) * ROW_;
            float x = 0.f;
#pragma unroll
            for (int p = 0; p < PARTS_; ++p) x += sp[p * ROW_ + tid];
            vsum = squash_row(x);
        } else {
            vsum = v_in[b * ROW_ + tid] + squash_row(s_red_prev[b * ROW_ + tid]);
        }
        if (T < 3 && part == 0) v_out[b * ROW_ + tid] = vsum;
        v_lds[tid] = vsum;
    }
    __syncthreads();

    float2 vv[5];
#pragma unroll
    for (int k = 0; k < 5; ++k)
        vv[k] = *(const float2*)&v_lds[32 * k + 2 * l];

    float2 sc[5];
#pragma unroll
    for (int k = 0; k < 5; ++k) { sc[k].x = 0.f; sc[k].y = 0.f; }

#define B_COMP(UW, uu) do {                                                 \
        const int su_ = (uu) * 16 + g;                                      \
        float own[5];                                                       \
        _Pragma("unroll")                                                   \
        for (int k = 0; k < 5; ++k) own[k] = b_lds[su_ * OC_ + 2 * k + h];  \
        _Pragma("unroll")                                                   \
        for (int k = 0; k < 5; ++k) {                                       \
            float pd = bf_lo(UW[k]) * vv[k].x + bf_hi(UW[k]) * vv[k].y;     \
            own[k] += dpp_sum8(pd);                                         \
        }                                                                   \
        const float inv = softmax10(own);                                   \
        _Pragma("unroll")                                                   \
        for (int k = 0; k < 5; ++k) {                                       \
            float c = own[k] * inv;                                         \
            sc[k].x += c * bf_lo(UW[k]); sc[k].y += c * bf_hi(UW[k]);       \
        }                                                                   \
    } while (0)

#pragma clang loop unroll(disable)
    for (int uu = 0; uu < UPB_ - 1; uu += 2) {     // uu = 0,2,4,6
        B_COMP(uwA, uu);
        if (uu + 2 < UPB_) B_LOAD(uwA, uu + 2);
        B_COMP(uwB, uu + 1);
        if (uu + 3 < UPB_) B_LOAD(uwB, uu + 3);
    }
    B_COMP(uwA, UPB_ - 1);                          // uu = 8
#undef B_LOAD
#undef B_COMP

#pragma unroll
    for (int k = 0; k < 5; ++k) {
        sc[k].x += __shfl_xor(sc[k].x, 16); sc[k].y += __shfl_xor(sc[k].y, 16);
        sc[k].x += __shfl_xor(sc[k].x, 32); sc[k].y += __shfl_xor(sc[k].y, 32);
    }
    if (lane < 16) {
#pragma unroll
        for (int k = 0; k < 5; ++k)
            *(float2*)&red[wave][32 * k + 2 * l] = sc[k];
    }
    __syncthreads();
    if (tid < ROW_) {
        float t = red[0][tid] + red[1][tid] + red[2][tid] + red[3][tid];
        atomicAdd(&s_out[b * ROW_ + tid], t);
    }
}

// ---------------- Kernel F ----------------
__global__ __launch_bounds__(256) void f_kernel(
    const float* __restrict__ s3, float* __restrict__ out)
{
    const int idx = blockIdx.x * 256 + threadIdx.x;   // 0..SOUT_-1
    out[idx] = squash_row(s3[idx]);
}

extern "C" void kernel_launch(void* const* d_in, const int* in_sizes, int n_in,
                              void* d_out, int out_size, void* d_ws, size_t ws_size,
                              hipStream_t stream) {
    const float* u    = (const float*)d_in[0];
    const float* b_in = (const float*)d_in[1];
    float* out = (float*)d_out;

    float*    s0_part = (float*)d_ws;                    // B_*8*160 = 163840 f32
    float*    s_red   = s0_part + (size_t)B_ * PARTS_ * ROW_; // 3*SOUT_ (T=1..3)
    float*    v_acc   = s_red + 3 * SOUT_;               // 2*SOUT_ (T=1,2)
    uint32_t* u16     = (uint32_t*)(v_acc + 2 * SOUT_);  // 47.2 MB

    const dim3 blk(256);
    const dim3 grid(B_ * PARTS_);      // 1024

    a_kernel<<<grid, blk, 0, stream>>>(u, b_in, u16, s0_part, s_red);
    i_kernel<1><<<grid, blk, 0, stream>>>(u16, b_in, s0_part, nullptr,
                                          nullptr, v_acc, s_red);
    i_kernel<2><<<grid, blk, 0, stream>>>(u16, b_in, s0_part, s_red,
                                          v_acc, v_acc + SOUT_, s_red + SOUT_);
    i_kernel<3><<<grid, blk, 0, stream>>>(u16, b_in, s0_part, s_red + SOUT_,
                                          v_acc + SOUT_, nullptr, s_red + 2 * SOUT_);
    f_kernel<<<dim3(SOUT_ / 256), blk, 0, stream>>>(s_red + 2 * SOUT_, out);
}